// Round 5
// baseline (190.543 us; speedup 1.0000x reference)
//
#include <hip/hip_runtime.h>

// Shapes: B=32, S_NEW=1, DIM=4096, H=32, KV=8, HD=128, PREV=2048, SEQ=2049
// All inputs/outputs fp32.
//
// ws layout (float offsets):
//   P1   [32][32][6144] @ 0        (6291456) qkv split-K partials
//   PA   [512][4160]    @ 0        (2129920) flash partials (ALIASES dead P1)
//   qkv  [32][6144]     @ 6291456  (196608)  rope'd q (scaled), k_new, v_new
//   attn [32][4096]     @ 6488064  (131072)  attention output (b, h, d)
//   P2   [32][32][4096] @ 6619136  (4194304) out-proj split-K partials

#define WS_P1   0
#define WS_PA   0
#define WS_QKV  6291456
#define WS_ATTN 6488064
#define WS_P2   6619136

// ---------------------------------------------------------------------------
// Skinny GEMM partial: P[ks][b][n] = sum_{k in 128-chunk} X[b][k] * W[k][n]
// grid: (Ntot/256, 32), block: 256 threads = 128 colpairs x 2 k-groups.
// ---------------------------------------------------------------------------
__global__ __launch_bounds__(256) void gemm_skinny(
    const float* __restrict__ X,
    const float* __restrict__ W0, int e0, int ld0,
    const float* __restrict__ W1, int e1, int ld1,
    const float* __restrict__ W2, int ld2,
    float* __restrict__ P, int Ntot)
{
    __shared__ float x_t[128][36];     // transposed x chunk [kk][b], pad 36
    __shared__ float2 red[128][33];    // 2-way kg reduce, pad 33

    const int nb = blockIdx.x * 256;
    const float* W; int ld, noff;
    if (nb < e0)      { W = W0; ld = ld0; noff = 0;  }
    else if (nb < e1) { W = W1; ld = ld1; noff = e0; }
    else              { W = W2; ld = ld2; noff = e1; }

    const int k0  = blockIdx.y * 128;
    const int tid = threadIdx.x;
    const int cp  = tid & 127;
    const int kg  = tid >> 7;
    const int nn  = nb - noff + cp * 2;

    #pragma unroll
    for (int i = 0; i < 16; ++i) {
        int idx = tid + i * 256;
        int bb = idx >> 7, kk = idx & 127;
        x_t[kk][bb] = X[(size_t)bb * 4096 + k0 + kk];
    }
    __syncthreads();

    float2 acc[32];
    #pragma unroll
    for (int b = 0; b < 32; ++b) { acc[b].x = 0.f; acc[b].y = 0.f; }

    const float* Wp = W + (size_t)k0 * ld + nn;
    for (int kk0 = kg * 64; kk0 < kg * 64 + 64; kk0 += 8) {
        float2 w[8];
        #pragma unroll
        for (int u = 0; u < 8; ++u)
            w[u] = *(const float2*)&Wp[(size_t)(kk0 + u) * ld];
        #pragma unroll
        for (int u = 0; u < 8; ++u) {
            const float* xr = x_t[kk0 + u];
            #pragma unroll
            for (int bq = 0; bq < 8; ++bq) {
                float4 xv = *(const float4*)&xr[bq * 4];
                acc[bq*4+0].x += xv.x * w[u].x; acc[bq*4+0].y += xv.x * w[u].y;
                acc[bq*4+1].x += xv.y * w[u].x; acc[bq*4+1].y += xv.y * w[u].y;
                acc[bq*4+2].x += xv.z * w[u].x; acc[bq*4+2].y += xv.z * w[u].y;
                acc[bq*4+3].x += xv.w * w[u].x; acc[bq*4+3].y += xv.w * w[u].y;
            }
        }
    }

    if (kg == 1) {
        #pragma unroll
        for (int b = 0; b < 32; ++b) red[cp][b] = acc[b];
    }
    __syncthreads();
    if (kg == 0) {
        const int ks = blockIdx.y;
        #pragma unroll
        for (int b = 0; b < 32; ++b) {
            float2 o = red[cp][b];
            float2 v; v.x = acc[b].x + o.x; v.y = acc[b].y + o.y;
            *(float2*)&P[((size_t)ks * 32 + b) * Ntot + nb + cp * 2] = v;
        }
    }
}

// ---------------------------------------------------------------------------
// Reduce 32 split-K partials for QKV + fused RoPE (+ 1/sqrt(128) on q).
// grid 768 x 128 (3 blocks/CU, balanced).
// ---------------------------------------------------------------------------
__global__ __launch_bounds__(128) void reduce_rope(
    const float* __restrict__ P, const float* __restrict__ freqs,
    float* __restrict__ qkv)
{
    int t = blockIdx.x * 128 + threadIdx.x;   // 0..98303
    int b = t / 3072;
    int cp = t - b * 3072;
    int n = cp * 2;
    float sx = 0.f, sy = 0.f;
    #pragma unroll
    for (int ks = 0; ks < 32; ++ks) {
        float2 v = *(const float2*)&P[((size_t)ks * 32 + b) * 6144 + n];
        sx += v.x; sy += v.y;
    }
    if (n < 5120) {
        int d = n & 127;
        float fr = freqs[d >> 1];
        float c = cosf(fr), s = sinf(fr);
        float ra = sx * c - sy * s;
        float rb = sx * s + sy * c;
        if (n < 4096) {
            const float sc = 0.08838834764831845f;  // 1/sqrt(128)
            ra *= sc; rb *= sc;
        }
        sx = ra; sy = rb;
    }
    float2 o; o.x = sx; o.y = sy;
    *(float2*)&qkv[(size_t)b * 6144 + n] = o;
}

// ---------------------------------------------------------------------------
// Contiguous-row flash attention. grid 512 = (b, chunk of 128 rows),
// block 256 (4 waves; wave w owns rows w*32..w*32+31 of the chunk).
// Each wave streams FULL 4KB cache rows (all 8 kv heads at once):
// lane l owns bytes [64l, 64l+64) of the row = (kv=l>>3, d-slice (l&7)*16).
// Emits per-chunk m[32], l[32], unnormalized o[32][128] (record 4160 floats).
// Chunk 15 also handles the new token (row index 128).
// ---------------------------------------------------------------------------
__global__ __launch_bounds__(256, 2) void attn_seq(
    const float* __restrict__ qkv,
    const float* __restrict__ ck, const float* __restrict__ cv,
    float* __restrict__ pa)
{
    __shared__ float sc[32 * 133 + 3];   // scores [kvh][row], stride 133
    __shared__ float scratch[3 * 4160];  // q_s (phase<=1) / wave-reduce (end)
    __shared__ float pm[32], pl[32];

    const int blk = blockIdx.x;
    const int cnk = blk & 15;
    const int b   = blk >> 4;
    const int tid = threadIdx.x;
    const int w   = tid >> 6, l = tid & 63;
    const int kv  = l >> 3, jj = l & 7;
    const bool tok = (cnk == 15) && (w == 3);

    // stage q (all 32 heads, pre-scaled) into LDS
    {
        const float* qb = qkv + (size_t)b * 6144 + tid * 16;
        float4 t0 = *(const float4*)(qb);
        float4 t1 = *(const float4*)(qb + 4);
        float4 t2 = *(const float4*)(qb + 8);
        float4 t3 = *(const float4*)(qb + 12);
        *(float4*)&scratch[tid * 16]      = t0;
        *(float4*)&scratch[tid * 16 + 4]  = t1;
        *(float4*)&scratch[tid * 16 + 8]  = t2;
        *(float4*)&scratch[tid * 16 + 12] = t3;
    }
    __syncthreads();
    float4 q4[4][4];
    #pragma unroll
    for (int h = 0; h < 4; ++h) {
        #pragma unroll
        for (int u = 0; u < 4; ++u)
            q4[h][u] = *(const float4*)&scratch[(kv * 4 + h) * 128 + jj * 16 + u * 4];
    }

    // -------- phase 1: scores, 2-row batched full-row streaming --------
    const float* kb_ = ck + ((size_t)b * 2048 + cnk * 128 + w * 32) * 1024 + l * 16;
    for (int t = 0; t < 32; t += 2) {
        float4 ka[2][4];
        #pragma unroll
        for (int r = 0; r < 2; ++r) {
            #pragma unroll
            for (int u = 0; u < 4; ++u)
                ka[r][u] = *(const float4*)(kb_ + (size_t)(t + r) * 1024 + u * 4);
        }
        #pragma unroll
        for (int r = 0; r < 2; ++r) {
            float p[4];
            #pragma unroll
            for (int h = 0; h < 4; ++h) {
                p[h] = q4[h][0].x*ka[r][0].x + q4[h][0].y*ka[r][0].y
                     + q4[h][0].z*ka[r][0].z + q4[h][0].w*ka[r][0].w
                     + q4[h][1].x*ka[r][1].x + q4[h][1].y*ka[r][1].y
                     + q4[h][1].z*ka[r][1].z + q4[h][1].w*ka[r][1].w
                     + q4[h][2].x*ka[r][2].x + q4[h][2].y*ka[r][2].y
                     + q4[h][2].z*ka[r][2].z + q4[h][2].w*ka[r][2].w
                     + q4[h][3].x*ka[r][3].x + q4[h][3].y*ka[r][3].y
                     + q4[h][3].z*ka[r][3].z + q4[h][3].w*ka[r][3].w;
            }
            #pragma unroll
            for (int off = 1; off < 8; off <<= 1) {
                #pragma unroll
                for (int h = 0; h < 4; ++h) p[h] += __shfl_xor(p[h], off);
            }
            if (jj == 0) {
                #pragma unroll
                for (int h = 0; h < 4; ++h)
                    sc[(kv * 4 + h) * 133 + w * 32 + t + r] = p[h];
            }
        }
    }
    if (tok) {   // new token: roped k_new from qkv, same row layout [kv][d]
        const float* kr = qkv + (size_t)b * 6144 + 4096 + l * 16;
        float4 ka[4];
        #pragma unroll
        for (int u = 0; u < 4; ++u) ka[u] = *(const float4*)(kr + u * 4);
        float p[4];
        #pragma unroll
        for (int h = 0; h < 4; ++h) {
            p[h] = q4[h][0].x*ka[0].x + q4[h][0].y*ka[0].y + q4[h][0].z*ka[0].z + q4[h][0].w*ka[0].w
                 + q4[h][1].x*ka[1].x + q4[h][1].y*ka[1].y + q4[h][1].z*ka[1].z + q4[h][1].w*ka[1].w
                 + q4[h][2].x*ka[2].x + q4[h][2].y*ka[2].y + q4[h][2].z*ka[2].z + q4[h][2].w*ka[2].w
                 + q4[h][3].x*ka[3].x + q4[h][3].y*ka[3].y + q4[h][3].z*ka[3].z + q4[h][3].w*ka[3].w;
        }
        #pragma unroll
        for (int off = 1; off < 8; off <<= 1) {
            #pragma unroll
            for (int h = 0; h < 4; ++h) p[h] += __shfl_xor(p[h], off);
        }
        if (jj == 0) {
            #pragma unroll
            for (int h = 0; h < 4; ++h) sc[(kv * 4 + h) * 133 + 128] = p[h];
        }
    }
    __syncthreads();

    // -------- partial softmax: wave w owns kvh = w*8 + (l>>3) --------
    {
        const int kvh = w * 8 + (l >> 3);
        const int j = l & 7;
        const int nrow = (cnk == 15) ? 129 : 128;
        float m = -1e30f;
        for (int s = j; s < nrow; s += 8) m = fmaxf(m, sc[kvh * 133 + s]);
        #pragma unroll
        for (int off = 1; off < 8; off <<= 1) m = fmaxf(m, __shfl_xor(m, off));
        float sum = 0.f;
        for (int s = j; s < nrow; s += 8) {
            float p = __expf(sc[kvh * 133 + s] - m);
            sc[kvh * 133 + s] = p;
            sum += p;
        }
        #pragma unroll
        for (int off = 1; off < 8; off <<= 1) sum += __shfl_xor(sum, off);
        if (j == 0) { pm[kvh] = m; pl[kvh] = sum; }
    }
    __syncthreads();

    // -------- phase 2: o += P * V, same full-row streaming --------
    float4 a4[4][4];
    #pragma unroll
    for (int h = 0; h < 4; ++h) {
        #pragma unroll
        for (int u = 0; u < 4; ++u) { a4[h][u].x=0.f; a4[h][u].y=0.f; a4[h][u].z=0.f; a4[h][u].w=0.f; }
    }
    const float* vb_ = cv + ((size_t)b * 2048 + cnk * 128 + w * 32) * 1024 + l * 16;
    for (int t = 0; t < 32; t += 2) {
        float4 va[2][4];
        #pragma unroll
        for (int r = 0; r < 2; ++r) {
            #pragma unroll
            for (int u = 0; u < 4; ++u)
                va[r][u] = *(const float4*)(vb_ + (size_t)(t + r) * 1024 + u * 4);
        }
        #pragma unroll
        for (int r = 0; r < 2; ++r) {
            const int row = w * 32 + t + r;
            float p[4];
            #pragma unroll
            for (int h = 0; h < 4; ++h) p[h] = sc[(kv * 4 + h) * 133 + row];
            #pragma unroll
            for (int h = 0; h < 4; ++h) {
                #pragma unroll
                for (int u = 0; u < 4; ++u) {
                    a4[h][u].x += p[h] * va[r][u].x;
                    a4[h][u].y += p[h] * va[r][u].y;
                    a4[h][u].z += p[h] * va[r][u].z;
                    a4[h][u].w += p[h] * va[r][u].w;
                }
            }
        }
    }
    if (tok) {
        const float* vr = qkv + (size_t)b * 6144 + 5120 + l * 16;
        float4 va[4];
        #pragma unroll
        for (int u = 0; u < 4; ++u) va[u] = *(const float4*)(vr + u * 4);
        float p[4];
        #pragma unroll
        for (int h = 0; h < 4; ++h) p[h] = sc[(kv * 4 + h) * 133 + 128];
        #pragma unroll
        for (int h = 0; h < 4; ++h) {
            #pragma unroll
            for (int u = 0; u < 4; ++u) {
                a4[h][u].x += p[h] * va[u].x;
                a4[h][u].y += p[h] * va[u].y;
                a4[h][u].z += p[h] * va[u].z;
                a4[h][u].w += p[h] * va[u].w;
            }
        }
    }
    __syncthreads();   // sc & q_s reads done; scratch becomes reduce buffer

    // -------- cross-wave reduce + PA record write --------
    if (w > 0) {
        float* dst = scratch + (w - 1) * 4160;
        #pragma unroll
        for (int h = 0; h < 4; ++h) {
            #pragma unroll
            for (int u = 0; u < 4; ++u)
                *(float4*)&dst[(kv * 4 + h) * 128 + jj * 16 + u * 4] = a4[h][u];
        }
    }
    __syncthreads();
    float* rec = pa + (size_t)blk * 4160;
    if (w == 0) {
        #pragma unroll
        for (int h = 0; h < 4; ++h) {
            #pragma unroll
            for (int u = 0; u < 4; ++u) {
                float4 v = a4[h][u];
                #pragma unroll
                for (int ww = 0; ww < 3; ++ww) {
                    float4 o = *(const float4*)&scratch[ww * 4160 + (kv * 4 + h) * 128 + jj * 16 + u * 4];
                    v.x += o.x; v.y += o.y; v.z += o.z; v.w += o.w;
                }
                *(float4*)&rec[64 + (kv * 4 + h) * 128 + jj * 16 + u * 4] = v;
            }
        }
    }
    if (tid < 32) { rec[tid] = pm[tid]; rec[32 + tid] = pl[tid]; }
}

// ---------------------------------------------------------------------------
// Combine 16 flash chunks per (b,kv). grid 256 = b*8+kv, block 128 (= d).
// ---------------------------------------------------------------------------
__global__ __launch_bounds__(128) void attn_combine(
    const float* __restrict__ pa, float* __restrict__ ao)
{
    __shared__ float wgt[16][4];   // [chunk][h] = exp(m_c - M) / L
    const int g = blockIdx.x;
    const int b = g >> 3, kv = g & 7;
    const int d = threadIdx.x;
    const float* base = pa + (size_t)b * 16 * 4160;

    if (d < 4) {
        const int kvh = kv * 4 + d;
        float M = -1e30f;
        #pragma unroll
        for (int c = 0; c < 16; ++c)
            M = fmaxf(M, base[(size_t)c * 4160 + kvh]);
        float L = 0.f;
        float e[16];
        #pragma unroll
        for (int c = 0; c < 16; ++c) {
            e[c] = __expf(base[(size_t)c * 4160 + kvh] - M);
            L += base[(size_t)c * 4160 + 32 + kvh] * e[c];
        }
        float inv = 1.0f / L;
        #pragma unroll
        for (int c = 0; c < 16; ++c) wgt[c][d] = e[c] * inv;
    }
    __syncthreads();

    #pragma unroll
    for (int h = 0; h < 4; ++h) {
        float v = 0.f;
        #pragma unroll
        for (int c = 0; c < 16; ++c)
            v += base[(size_t)c * 4160 + 64 + (kv * 4 + h) * 128 + d] * wgt[c][h];
        ao[(size_t)b * 4096 + kv * 512 + h * 128 + d] = v;
    }
}

// ---------------------------------------------------------------------------
// Reduce 32 split-K partials for output projection -> d_out
// grid 512 x 128 (2 blocks/CU, balanced).
// ---------------------------------------------------------------------------
__global__ __launch_bounds__(128) void reduce_out(
    const float* __restrict__ P, float* __restrict__ out)
{
    int t = blockIdx.x * 128 + threadIdx.x;   // float2 units, 0..65535
    int b = t >> 11;
    int cp = t & 2047;
    int n = cp * 2;
    float sx = 0.f, sy = 0.f;
    #pragma unroll
    for (int ks = 0; ks < 32; ++ks) {
        float2 v = *(const float2*)&P[((size_t)ks * 32 + b) * 4096 + n];
        sx += v.x; sy += v.y;
    }
    float2 o; o.x = sx; o.y = sy;
    *(float2*)&out[(size_t)b * 4096 + n] = o;
}

extern "C" void kernel_launch(void* const* d_in, const int* in_sizes, int n_in,
                              void* d_out, int out_size, void* d_ws, size_t ws_size,
                              hipStream_t stream) {
    const float* x  = (const float*)d_in[0];
    const float* wq = (const float*)d_in[1];
    const float* wk = (const float*)d_in[2];
    const float* wv = (const float*)d_in[3];
    const float* wo = (const float*)d_in[4];
    const float* ck = (const float*)d_in[5];
    const float* cv = (const float*)d_in[6];
    const float* fr = (const float*)d_in[7];
    float* out = (float*)d_out;
    float* ws  = (float*)d_ws;

    float* P1   = ws + WS_P1;
    float* PA   = ws + WS_PA;    // aliases P1 (dead after reduce_rope)
    float* qkv  = ws + WS_QKV;
    float* attn = ws + WS_ATTN;
    float* P2   = ws + WS_P2;

    dim3 g1(24, 32);
    gemm_skinny<<<g1, 256, 0, stream>>>(x, wq, 4096, 4096, wk, 5120, 1024,
                                        wv, 1024, P1, 6144);
    reduce_rope<<<768, 128, 0, stream>>>(P1, fr, qkv);
    attn_seq<<<512, 256, 0, stream>>>(qkv, ck, cv, PA);
    attn_combine<<<256, 128, 0, stream>>>(PA, attn);
    dim3 g4(16, 32);
    gemm_skinny<<<g4, 256, 0, stream>>>(attn, wo, 4096, 4096, wo, 4096, 4096,
                                        wo, 4096, P2, 4096);
    reduce_out<<<512, 128, 0, stream>>>(P2, out);
}